// Round 12
// baseline (126.900 us; speedup 1.0000x reference)
//
#include <hip/hip_runtime.h>
#include <math.h>

#define CIN 3
#define DIN 16
#define HIN 128
#define WIN 128
#define COUT 24
#define HOUT 126
#define DOUT 14
#define HW (HIN * WIN)

using f16x8 = __attribute__((ext_vector_type(8))) _Float16;
using f32x4 = __attribute__((ext_vector_type(4))) float;

// Row-order im2col (R7/R10 layout, proven): 162 rows x 16 px, row stride 18
// halves (0 bank conflicts measured). Register-cached A-frags (R10, proven).
#define ROWSTRIDE 18
#define SLOT_HALVES (162 * ROWSTRIDE)            // 2916
#define TAIL 96
#define LDS_HALVES (2 * SLOT_HALVES + TAIL)

// R12 = R10 + depth-2 prefetch: slice dp+4 loaded at dp (ping-pong stash),
// ds_written at dp+1. Loop barrier = lgkmcnt(0)-only + raw s_barrier so the
// in-flight global loads are NOT drained (hipcc's __syncthreads emits
// vmcnt(0) which would kill the pipeline).
__global__ __launch_bounds__(256) void conv3d_min_softmax_mfma(
    const float* __restrict__ x,
    const float* __restrict__ wgt,
    const float* __restrict__ bias,
    float* __restrict__ out)
{
    __shared__ _Float16 imX[LDS_HALVES];

    const int tid  = threadIdx.x;
    const int wv   = tid >> 6;
    const int lane = tid & 63;
    const int cl   = lane & 15;   // A: px-lane | B/C: co-lane
    const int kg   = lane >> 4;   // A/B: k-group | C: px-row-group
    const bool has11 = (tid < 32);

    const int wchunk = blockIdx.x;
    const int band   = blockIdx.y;
    const int b      = blockIdx.z;
    const int w0 = (wchunk < 7) ? wchunk * 16 : 110;
    const int h0 = (band   < 7) ? band   * 16 : 110;

    const float* xb = x + (size_t)b * (CIN * DIN * HW);

    for (int i = 2 * SLOT_HALVES + tid; i < LDS_HALVES; i += 256)
        imX[i] = (_Float16)0.f;

    // ---- B-fragments (weights); k-order = kh*9 + ci*3 + kw; pads -> 0
    f16x8 bw[3][2];
    #pragma unroll
    for (int kd = 0; kd < 3; ++kd)
      #pragma unroll
      for (int hf = 0; hf < 2; ++hf)
        #pragma unroll
        for (int j = 0; j < 8; ++j) {
          int k  = kg * 8 + j;
          int co = hf * 16 + cl;
          float wvv = 0.f;
          if (k < 27 && co < 24) {
            int kh = k / 9, rem = k - kh * 9, ci = rem / 3, kw = rem - ci * 3;
            wvv = wgt[((co * 3 + ci) * 3 + kd) * 9 + kh * 3 + kw];
          }
          bw[kd][hf][j] = (_Float16)wvv;
        }

    const float bias0 = bias[cl];
    const float bias1 = (cl < 8) ? bias[16 + cl] : 0.f;

    // ---- builder offsets: elems e = tid + it*256, it=0..10 (it==10 iff tid<32)
    int goff[11];
    int lidx[11];
    #pragma unroll
    for (int it = 0; it < 11; ++it) {
      int e = tid + it * 256;
      int ec = (e < 2592) ? e : 0;
      int hrow = ec / 144, e2 = ec - hrow * 144;
      int ci   = e2 / 48,  e3 = e2 - ci * 48;
      int kw   = e3 >> 4,  px = e3 & 15;
      goff[it] = (ci * DIN) * HW + (h0 + hrow) * WIN + (w0 + kw + px);
      lidx[it] = (hrow * 9 + ci * 3 + kw) * ROWSTRIDE + px;
    }

    int rbase[4];
    #pragma unroll
    for (int t = 0; t < 4; ++t)
      rbase[t] = ((wv * 4 + t) * 9 + kg * 8) * ROWSTRIDE + cl;

#define STAGE_LOAD(SL, s)                                   \
    { _Pragma("unroll")                                     \
      for (int it = 0; it < 10; ++it)                       \
        SL[it] = xb[goff[it] + (s) * HW];                   \
      if (has11) SL[10] = xb[goff[10] + (s) * HW]; }

#define STAGE_WRITE(SW, sb)                                 \
    { _Pragma("unroll")                                     \
      for (int it = 0; it < 10; ++it)                       \
        imX[(sb) + lidx[it]] = (_Float16)SW[it];            \
      if (has11) imX[(sb) + lidx[10]] = (_Float16)SW[10]; }

    // ---- prologue: slices 0,1 -> slots 0,1; gather A0,A1; slice 2 -> slot 0;
    // gather A2; then issue stashA <- slice 3 (stays in flight into the loop).
    #pragma unroll 1
    for (int s = 0; s < 2; ++s) {
      #pragma unroll
      for (int it = 0; it < 10; ++it)
        imX[s * SLOT_HALVES + lidx[it]] = (_Float16)xb[goff[it] + s * HW];
      if (has11)
        imX[s * SLOT_HALVES + lidx[10]] = (_Float16)xb[goff[10] + s * HW];
    }
    __syncthreads();

    f16x8 A0[4], A1[4], A2[4];
    #pragma unroll
    for (int t = 0; t < 4; ++t)
      #pragma unroll
      for (int j = 0; j < 8; ++j) {
        A0[t][j] = imX[0 * SLOT_HALVES + rbase[t] + j * ROWSTRIDE];
        A1[t][j] = imX[1 * SLOT_HALVES + rbase[t] + j * ROWSTRIDE];
      }
    __syncthreads();

    #pragma unroll
    for (int it = 0; it < 10; ++it)
      imX[0 * SLOT_HALVES + lidx[it]] = (_Float16)xb[goff[it] + 2 * HW];
    if (has11)
      imX[0 * SLOT_HALVES + lidx[10]] = (_Float16)xb[goff[10] + 2 * HW];
    __syncthreads();

    #pragma unroll
    for (int t = 0; t < 4; ++t)
      #pragma unroll
      for (int j = 0; j < 8; ++j)
        A2[t][j] = imX[0 * SLOT_HALVES + rbase[t] + j * ROWSTRIDE];

    float stashA[11], stashB[11];
    STAGE_LOAD(stashA, 3);

    float mn[4][2][4];
    #pragma unroll
    for (int t = 0; t < 4; ++t)
      #pragma unroll
      for (int hf = 0; hf < 2; ++hf)
        #pragma unroll
        for (int j = 0; j < 4; ++j) mn[t][hf][j] = 3.4e38f;

    // Invariant entering dp: A0/A1/A2 = slices dp..dp+2; SW = slice dp+3
    // (loads issued at dp-1, still possibly in flight); SL = free.
#define DP_BODY(dp, SW, SL)                                              \
    {                                                                    \
      if ((dp) < 12) STAGE_LOAD(SL, (dp) + 4);                           \
      _Pragma("unroll")                                                  \
      for (int t = 0; t < 4; ++t) {                                      \
        f32x4 z = {0.f, 0.f, 0.f, 0.f};                                  \
        f32x4 acc0 = __builtin_amdgcn_mfma_f32_16x16x32_f16(A0[t], bw[0][0], z, 0, 0, 0); \
        f32x4 acc1 = __builtin_amdgcn_mfma_f32_16x16x32_f16(A0[t], bw[0][1], z, 0, 0, 0); \
        acc0 = __builtin_amdgcn_mfma_f32_16x16x32_f16(A1[t], bw[1][0], acc0, 0, 0, 0);    \
        acc1 = __builtin_amdgcn_mfma_f32_16x16x32_f16(A1[t], bw[1][1], acc1, 0, 0, 0);    \
        acc0 = __builtin_amdgcn_mfma_f32_16x16x32_f16(A2[t], bw[2][0], acc0, 0, 0, 0);    \
        acc1 = __builtin_amdgcn_mfma_f32_16x16x32_f16(A2[t], bw[2][1], acc1, 0, 0, 0);    \
        _Pragma("unroll")                                                \
        for (int j = 0; j < 4; ++j) {                                    \
          mn[t][0][j] = fminf(mn[t][0][j], acc0[j]);                     \
          mn[t][1][j] = fminf(mn[t][1][j], acc1[j]);                     \
        }                                                                \
      }                                                                  \
      if ((dp) < 13) {                                                   \
        const int sb = (((dp) + 1) & 1) * SLOT_HALVES;                   \
        STAGE_WRITE(SW, sb);                                             \
        asm volatile("s_waitcnt lgkmcnt(0)" ::: "memory");               \
        __builtin_amdgcn_s_barrier();                                    \
        _Pragma("unroll")                                                \
        for (int t = 0; t < 4; ++t) { A0[t] = A1[t]; A1[t] = A2[t]; }    \
        _Pragma("unroll")                                                \
        for (int t = 0; t < 4; ++t)                                      \
          _Pragma("unroll")                                              \
          for (int j = 0; j < 8; ++j)                                    \
            A2[t][j] = imX[sb + rbase[t] + j * ROWSTRIDE];               \
      }                                                                  \
    }

    #pragma unroll 1
    for (int dpe = 0; dpe < DOUT; dpe += 2) {
      DP_BODY(dpe,     stashA, stashB);   // even: write A, load B
      DP_BODY(dpe + 1, stashB, stashA);   // odd:  write B, load A
    }

    // ---- fused bias + softmax over channels (cross-lane over 16-lane group)
    float* ob = out + (size_t)b * COUT * HOUT * HOUT;
    #pragma unroll
    for (int t = 0; t < 4; ++t) {
      const int h = h0 + wv * 4 + t;
      #pragma unroll
      for (int j = 0; j < 4; ++j) {
        float v0 = mn[t][0][j] + bias0;
        float v1 = (cl < 8) ? (mn[t][1][j] + bias1) : -3.4e38f;
        float mx = fmaxf(v0, v1);
        #pragma unroll
        for (int msk = 1; msk < 16; msk <<= 1)
          mx = fmaxf(mx, __shfl_xor(mx, msk));
        float e0 = __expf(v0 - mx);
        float e1 = (cl < 8) ? __expf(v1 - mx) : 0.f;
        float sm = e0 + e1;
        #pragma unroll
        for (int msk = 1; msk < 16; msk <<= 1)
          sm += __shfl_xor(sm, msk);
        float r = 1.f / sm;
        const int w = w0 + kg * 4 + j;
        ob[((size_t)cl * HOUT + h) * HOUT + w] = e0 * r;
        if (cl < 8)
          ob[((size_t)(16 + cl) * HOUT + h) * HOUT + w] = e1 * r;
      }
    }
}

extern "C" void kernel_launch(void* const* d_in, const int* in_sizes, int n_in,
                              void* d_out, int out_size, void* d_ws, size_t ws_size,
                              hipStream_t stream) {
    const float* x    = (const float*)d_in[0];
    const float* wgt  = (const float*)d_in[1];
    const float* bias = (const float*)d_in[2];
    float* out        = (float*)d_out;

    dim3 grid(8, 8, 16);   // (wchunk, band, b)
    dim3 block(256);
    conv3d_min_softmax_mfma<<<grid, block, 0, stream>>>(x, wgt, bias, out);
}

// Round 17
// 84.685 us; speedup vs baseline: 1.4985x; 1.4985x over previous
//
#include <hip/hip_runtime.h>
#include <math.h>

#define CIN 3
#define DIN 16
#define HIN 128
#define WIN 128
#define COUT 24
#define HOUT 126
#define DOUT 14
#define HW (HIN * WIN)

using f16x8  = __attribute__((ext_vector_type(8))) _Float16;
using fp16x2 = __attribute__((ext_vector_type(2))) __fp16;   // cvt_pkrtz return type
using f32x4  = __attribute__((ext_vector_type(4))) float;

// R17 = R13 with the wave-row bug fixed: voff now includes wv*4 (each wave owns
// output rows h0+wv*4 .. +3). NO LDS, NO barriers. Direct global A-fragment
// loads (L1/L2 absorb kh/kw duplication); kd-reuse via AX/AY/AZ rotation.
__global__ __launch_bounds__(256) void conv3d_min_softmax_mfma(
    const float* __restrict__ x,
    const float* __restrict__ wgt,
    const float* __restrict__ bias,
    float* __restrict__ out)
{
    const int tid  = threadIdx.x;
    const int wv   = tid >> 6;
    const int lane = tid & 63;
    const int cl   = lane & 15;   // A: px-lane | B/C: co-lane
    const int kg   = lane >> 4;   // A/B: k-group | C: px-row-group

    const int wchunk = blockIdx.x;
    const int band   = blockIdx.y;
    const int b      = blockIdx.z;
    const int w0 = (wchunk < 7) ? wchunk * 16 : 110;   // overlap: identical math, benign
    const int h0 = (band   < 7) ? band   * 16 : 110;

    const float* xb = x + (size_t)b * (CIN * DIN * HW);

    // ---- B-fragments; k-order = ci*9 + kh*3 + kw; pads -> 0
    f16x8 bw[3][2];   // [kd][co-half]
    #pragma unroll
    for (int kd = 0; kd < 3; ++kd)
      #pragma unroll
      for (int hf = 0; hf < 2; ++hf)
        #pragma unroll
        for (int j = 0; j < 8; ++j) {
          int k  = kg * 8 + j;
          int co = hf * 16 + cl;
          float wvv = 0.f;
          if (k < 27 && co < 24) {
            int ci = k / 9, rem = k - ci * 9, kh = rem / 3, kw = rem - kh * 3;
            wvv = wgt[((co * 3 + ci) * 3 + kd) * 9 + kh * 3 + kw];
          }
          bw[kd][hf][j] = (_Float16)wvv;
        }

    const float bias0 = bias[cl];
    const float bias1 = (cl < 8) ? bias[16 + cl] : 0.f;

    // ---- per-thread A-fragment element offsets (slice- and tile-invariant).
    // Wave wv owns output rows h0 + wv*4 + t; tile delta is +t*WIN (imm-foldable).
    int voff[8];
    #pragma unroll
    for (int j = 0; j < 8; ++j) {
      int k = kg * 8 + j;
      if (k < 27) {
        int ci = k / 9, rem = k - ci * 9, kh = rem / 3, kw = rem - kh * 3;
        voff[j] = ci * (DIN * HW) + (h0 + wv * 4 + kh) * WIN + (w0 + kw + cl);
      } else {
        voff[j] = 0;   // pad: any finite x value; weight is 0
      }
    }

    float mn[4][2][4];
    #pragma unroll
    for (int t = 0; t < 4; ++t)
      #pragma unroll
      for (int hf = 0; hf < 2; ++hf)
        #pragma unroll
        for (int j = 0; j < 4; ++j) mn[t][hf][j] = 3.4e38f;

    f16x8 AX[4], AY[4], AZ[4];
    float R[4][8];

#define LOADS(s)                                                         \
    { const float* xs = xb + (s) * HW;                                   \
      _Pragma("unroll")                                                  \
      for (int t = 0; t < 4; ++t)                                        \
        _Pragma("unroll")                                                \
        for (int j = 0; j < 8; ++j)                                      \
          R[t][j] = xs[voff[j] + t * WIN]; }

#define PACK(Aa)                                                         \
    { _Pragma("unroll")                                                  \
      for (int t = 0; t < 4; ++t) {                                      \
        union { f16x8 v; fp16x2 h[4]; } u;                               \
        u.h[0] = __builtin_amdgcn_cvt_pkrtz(R[t][0], R[t][1]);           \
        u.h[1] = __builtin_amdgcn_cvt_pkrtz(R[t][2], R[t][3]);           \
        u.h[2] = __builtin_amdgcn_cvt_pkrtz(R[t][4], R[t][5]);           \
        u.h[3] = __builtin_amdgcn_cvt_pkrtz(R[t][6], R[t][7]);           \
        Aa[t] = u.v; } }

#define MFMAMIN(Aa, Ab, Ac)                                              \
    { _Pragma("unroll")                                                  \
      for (int t = 0; t < 4; ++t) {                                      \
        f32x4 z = {0.f, 0.f, 0.f, 0.f};                                  \
        f32x4 acc0 = __builtin_amdgcn_mfma_f32_16x16x32_f16(Aa[t], bw[0][0], z, 0, 0, 0); \
        f32x4 acc1 = __builtin_amdgcn_mfma_f32_16x16x32_f16(Aa[t], bw[0][1], z, 0, 0, 0); \
        acc0 = __builtin_amdgcn_mfma_f32_16x16x32_f16(Ab[t], bw[1][0], acc0, 0, 0, 0);    \
        acc1 = __builtin_amdgcn_mfma_f32_16x16x32_f16(Ab[t], bw[1][1], acc1, 0, 0, 0);    \
        acc0 = __builtin_amdgcn_mfma_f32_16x16x32_f16(Ac[t], bw[2][0], acc0, 0, 0, 0);    \
        acc1 = __builtin_amdgcn_mfma_f32_16x16x32_f16(Ac[t], bw[2][1], acc1, 0, 0, 0);    \
        _Pragma("unroll")                                                \
        for (int j = 0; j < 4; ++j) {                                    \
          mn[t][0][j] = fminf(mn[t][0][j], acc0[j]);                     \
          mn[t][1][j] = fminf(mn[t][1][j], acc1[j]);                     \
        } } }

    // ---- prologue: slices 0,1,2 -> AX,AY,AZ
    LOADS(0); PACK(AX);
    LOADS(1); PACK(AY);
    LOADS(2); PACK(AZ);

    // ---- main: 4 trios (dp 0..11), statically rotated; loads for slice dp+3
    // issued before the MFMA phase, packed after (T14: latency hides under MFMA).
    #pragma unroll 1
    for (int dpe = 0; dpe < 12; dpe += 3) {
      LOADS(dpe + 3); MFMAMIN(AX, AY, AZ); PACK(AX);
      LOADS(dpe + 4); MFMAMIN(AY, AZ, AX); PACK(AY);
      LOADS(dpe + 5); MFMAMIN(AZ, AX, AY); PACK(AZ);
    }
    // dp = 12 (slices 12,13,14; prefetch slice 15), dp = 13 (slices 13,14,15)
    LOADS(15); MFMAMIN(AX, AY, AZ); PACK(AX);
    MFMAMIN(AY, AZ, AX);

    // ---- fused bias + softmax over channels (cross-lane over 16-lane group)
    float* ob = out + (size_t)b * COUT * HOUT * HOUT;
    #pragma unroll
    for (int t = 0; t < 4; ++t) {
      const int h = h0 + wv * 4 + t;
      #pragma unroll
      for (int j = 0; j < 4; ++j) {
        float v0 = mn[t][0][j] + bias0;
        float v1 = (cl < 8) ? (mn[t][1][j] + bias1) : -3.4e38f;
        float mx = fmaxf(v0, v1);
        #pragma unroll
        for (int msk = 1; msk < 16; msk <<= 1)
          mx = fmaxf(mx, __shfl_xor(mx, msk));
        float e0 = __expf(v0 - mx);
        float e1 = (cl < 8) ? __expf(v1 - mx) : 0.f;
        float sm = e0 + e1;
        #pragma unroll
        for (int msk = 1; msk < 16; msk <<= 1)
          sm += __shfl_xor(sm, msk);
        float r = 1.f / sm;
        const int w = w0 + kg * 4 + j;
        ob[((size_t)cl * HOUT + h) * HOUT + w] = e0 * r;
        if (cl < 8)
          ob[((size_t)(16 + cl) * HOUT + h) * HOUT + w] = e1 * r;
      }
    }
}

extern "C" void kernel_launch(void* const* d_in, const int* in_sizes, int n_in,
                              void* d_out, int out_size, void* d_ws, size_t ws_size,
                              hipStream_t stream) {
    const float* x    = (const float*)d_in[0];
    const float* wgt  = (const float*)d_in[1];
    const float* bias = (const float*)d_in[2];
    float* out        = (float*)d_out;

    dim3 grid(8, 8, 16);   // (wchunk, band, b)
    dim3 block(256);
    conv3d_min_softmax_mfma<<<grid, block, 0, stream>>>(x, wgt, bias, out);
}